// Round 27
// baseline (193.115 us; speedup 1.0000x reference)
//
#include <hip/hip_runtime.h>
#include <stdint.h>
#include <limits.h>

// StackMachineCell — fused, scalar-chain producer (round 27).
// r26 win (flag handoff, 1P+7C: e2e 152; producer-bound ~600cy/step).
// This round deletes the two big chain terms:
//  1) stack -> 5 scalar u64 BITPLANES (64 entries x 5 bits): stack[npn] =
//     15 SALU bit-extracts (~60cy scalar pipe) replacing ds_bpermute
//     (~100-120cy DS round-trip). Bit-identical to at[npn].set + read.
//  2) fully scalar chain: packed inputs preloaded to 8 VGPRs (readlane per
//     step, register-only); LUT widened to u32 so the uniform-address load
//     emits s_load_dword (r6 precedent); readfirstlane pins it scalar.
// Chain = s_load(~200) + ~30 SALU -> ~300cy non-forced / ~80 forced.
// Consumers verbatim r26 (nt stores). Trajectory bit-identical.
// ws: Mm32@0 | Ms32@17408 | Mb32@50176 | MmT@115712 | MsT@133120 |
//     lut u32 @165888 (1MB)  (total 1214464 B; guarded).

#define TT 512
#define BB 512
#define HH 128
#define NSs 64
#define NMm 34
#define NBb 128

typedef unsigned short u16;
typedef unsigned long long u64;
typedef float f2 __attribute__((ext_vector_type(2)));

// ---- precompute M tables (f64 accumulate, f32 store; + transposed copies)
__global__ __launch_bounds__(256) void precompute_M(
    const float* __restrict__ embed,
    const float* __restrict__ Wm, const float* __restrict__ bm,
    const float* __restrict__ Wb, const float* __restrict__ bb,
    const float* __restrict__ Ws, const float* __restrict__ bs,
    float* __restrict__ Mm32, float* __restrict__ Ms32,
    float* __restrict__ Mb32, float* __restrict__ MmT,
    float* __restrict__ MsT) {
  __shared__ double e[HH];
  const int v = blockIdx.x;
  const int tid = threadIdx.x;  // 256
  if (tid < HH) e[tid] = (double)embed[v * HH + tid];
  __syncthreads();
  if (tid < NMm) {
    const int j = tid;
    double acc = 0.0;
    for (int h = 0; h < HH; ++h) acc += e[h] * (double)Wm[h * NMm + j];
    const float r = (float)(acc + (double)bm[j]);
    Mm32[v * NMm + j] = r;
    MmT[j * 128 + v] = r;
  } else if (tid < NMm + NSs) {
    const int j = tid - NMm;
    double acc = 0.0;
    for (int h = 0; h < HH; ++h) acc += e[h] * (double)Ws[h * NSs + j];
    const float r = (float)(acc + (double)bs[j]);
    Ms32[v * NSs + j] = r;
    MsT[j * 128 + v] = r;
  } else if (tid < NMm + NSs + NBb) {
    const int j = tid - NMm - NSs;
    double acc = 0.0;
    for (int h = 0; h < HH; ++h) acc += e[h] * (double)Wb[h * NBb + j];
    Mb32[v * NBb + j] = (float)(acc + (double)bb[j]);
  }
}

// ---- build decision LUT (u32): block = (s,r) pair, thread = v.
// Bit-identical decisions to r12-r26; wider container for s_load_dword.
__global__ __launch_bounds__(128) void build_lut(
    const float* __restrict__ Wm, const float* __restrict__ Ws,
    const float* __restrict__ MmT, const float* __restrict__ MsT,
    unsigned* __restrict__ lut) {
  __shared__ float wms[NMm], wmr[NMm], wss[NSs], wsr[NSs];  // 784 B
  const int s = blockIdx.x >> 5;    // 0..63
  const int r = blockIdx.x & 31;    // 0..31
  const int tid = threadIdx.x;      // 128 = one v per thread
  if (tid < NMm) {
    wms[tid] = Wm[(128 + s) * NMm + tid];
    wmr[tid] = Wm[(192 + r) * NMm + tid];
  }
  if (tid < NSs) {
    wss[tid] = Ws[(128 + s) * NSs + tid];
    wsr[tid] = Ws[(192 + r) * NSs + tid];
  }
  __syncthreads();

  const int v = tid;
  int bestm = INT_MIN, act = 0;
#pragma unroll
  for (int j = 0; j < NMm; ++j) {
    const double val = (double)MmT[j * 128 + v] + (double)wms[j] + (double)wmr[j];
    const int iv = (int)(val * 67108864.0);
    if (iv > bestm) { bestm = iv; act = j; }
  }
  int bests = INT_MIN, ns = 0;
#pragma unroll
  for (int j = 0; j < NSs; ++j) {
    const double val = (double)MsT[j * 128 + v] + (double)wss[j] + (double)wsr[j];
    const int iv = (int)(val * 67108864.0);
    if (iv > bests) { bests = iv; ns = j; }
  }
  lut[(unsigned)blockIdx.x * 128 + v] = (unsigned)(act | (ns << 6));
}

// ---- fused: 512 blocks x 512 threads, ONE chain per block.
// Wave 0 = producer (scalar chain: bitplane stack, readlane inputs,
// s_load LUT); waves 1-7 = consumers (rows t mod 7, nt stores).
// trajL doubles as progress flag (0xFFFF = not ready).
__global__ __launch_bounds__(512, 1) void sm_fused(
    const int* __restrict__ x, const int* __restrict__ tact,
    const int* __restrict__ tstate, const int* __restrict__ forc,
    const unsigned* __restrict__ lut,
    const float* __restrict__ Wm, const float* __restrict__ Wb,
    const float* __restrict__ Ws,
    const float* __restrict__ Mm32, const float* __restrict__ Ms32,
    const float* __restrict__ Mb32, float* __restrict__ out) {
  __shared__ unsigned sPk[TT];          // 2048 B
  __shared__ volatile u16 trajL[TT];    // 1024 B (flag+data in one u16)
  const int tid = threadIdx.x;
  const int b = blockIdx.x;
  for (int t = tid; t < TT; t += 512) {
    const int g = t * BB + b;
    sPk[t] = (unsigned)x[g] | ((unsigned)tact[g] << 8) |
             ((unsigned)tstate[g] << 16) | ((unsigned)forc[g] << 24);
    trajL[t] = 0xFFFFu;
  }
  __syncthreads();  // last barrier; roles diverge below

  const int lane = tid & 63;
  const int w = tid >> 6;

  if (w == 0) {
    // ===== producer: fully scalar chain =================================
    __builtin_amdgcn_s_setprio(1);
    // preload packed inputs: reg g holds steps g*64 + lane
    unsigned pk0 = sPk[0 * 64 + lane], pk1 = sPk[1 * 64 + lane];
    unsigned pk2 = sPk[2 * 64 + lane], pk3 = sPk[3 * 64 + lane];
    unsigned pk4 = sPk[4 * 64 + lane], pk5 = sPk[5 * 64 + lane];
    unsigned pk6 = sPk[6 * 64 + lane], pk7 = sPk[7 * 64 + lane];

    u64 pl0 = 0, pl1 = 0, pl2 = 0, pl3 = 0, pl4 = 0;  // stack bitplanes
    int ptr = 0, rr = 0, s = 0;

#pragma unroll
    for (int g2 = 0; g2 < 8; ++g2) {
      const unsigned preg = (g2 == 0) ? pk0 : (g2 == 1) ? pk1
                          : (g2 == 2) ? pk2 : (g2 == 3) ? pk3
                          : (g2 == 4) ? pk4 : (g2 == 5) ? pk5
                          : (g2 == 6) ? pk6 : pk7;
      for (int t2 = 0; t2 < 64; ++t2) {
        const int t = g2 * 64 + t2;
        const unsigned pk =
            (unsigned)__builtin_amdgcn_readlane((int)preg, t2);

        // publish carry-in (s, rr) — the ds_write IS the release
        if (lane == 0) trajL[t] = (u16)(s | (rr << 8));

        int act, ns;
        if (pk >> 24) {  // forced: all scalar
          act = (int)((pk >> 8) & 63u);
          ns = (int)((pk >> 16) & 63u);
        } else {
          const int idx = s * 4096 + rr * 128 + (int)(pk & 127u);
          const int lv = __builtin_amdgcn_readfirstlane((int)lut[idx]);
          act = lv & 63;
          ns = (lv >> 6) & 63;
        }

        const bool ispush = act >= 2;
        int npn = ptr + (ispush ? 1 : 0) - (act == 1 ? 1 : 0);
        npn = npn < 0 ? 0 : (npn > 63 ? 63 : npn);
        if (ispush) {  // stack[npn] = sym  (bit-set in 5 planes)
          const unsigned sym = (unsigned)(act - 2);
          const u64 m = ~(1ULL << npn);
          pl0 = (pl0 & m) | ((u64)(sym & 1u) << npn);
          pl1 = (pl1 & m) | ((u64)((sym >> 1) & 1u) << npn);
          pl2 = (pl2 & m) | ((u64)((sym >> 2) & 1u) << npn);
          pl3 = (pl3 & m) | ((u64)((sym >> 3) & 1u) << npn);
          pl4 = (pl4 & m) | ((u64)((sym >> 4) & 1u) << npn);
        }
        // rr = stack[npn]  (bit-extract from 5 planes, scalar)
        rr = (int)(((pl0 >> npn) & 1) | (((pl1 >> npn) & 1) << 1) |
                   (((pl2 >> npn) & 1) << 2) | (((pl3 >> npn) & 1) << 3) |
                   (((pl4 >> npn) & 1) << 4));
        ptr = npn;
        s = ns;
      }
    }
  } else {
    // ======= consumer: 7 waves, rows t = j, j+7, ... (r26 verbatim) =====
    const int j = w - 1;   // 0..6
    float* outLM = out;                                  // [T,B,34]
    float* outLB = out + (size_t)TT * BB * NMm;          // [T,B,128]
    float* outLS = out + (size_t)TT * BB * (NMm + NBb);  // [T,B,64]

    for (int t = j; t < TT; t += 7) {
      int pr = trajL[t];
      while (pr == 0xFFFF) {            // flag: row not yet published
        __builtin_amdgcn_s_sleep(4);
        pr = trajL[t];
      }
      const unsigned pk = sPk[t];
      const int xv = (int)(pk & 127u);
      const int s = pr & 255;
      const int r = pr >> 8;
      const int rs = 128 + s, rr = 192 + r;
      const int row = t * BB + b;
      if (lane < NMm)
        __builtin_nontemporal_store(
            Mm32[xv * NMm + lane] + Wm[rs * NMm + lane] + Wm[rr * NMm + lane],
            &outLM[(size_t)row * NMm + lane]);
      __builtin_nontemporal_store(
          Ms32[xv * NSs + lane] + Ws[rs * NSs + lane] + Ws[rr * NSs + lane],
          &outLS[(size_t)row * NSs + lane]);
      const f2 mb  = *(const f2*)&Mb32[xv * NBb + 2 * lane];
      const f2 wbs = *(const f2*)&Wb[rs * NBb + 2 * lane];
      const f2 wbr = *(const f2*)&Wb[rr * NBb + 2 * lane];
      f2 o;
      o.x = mb.x + wbs.x + wbr.x;   // same per-element add order as r14-r26
      o.y = mb.y + wbs.y + wbr.y;
      __builtin_nontemporal_store(o, (f2*)&outLB[(size_t)row * NBb + 2 * lane]);
    }
  }
}

extern "C" void kernel_launch(void* const* d_in, const int* in_sizes, int n_in,
                              void* d_out, int out_size, void* d_ws, size_t ws_size,
                              hipStream_t stream) {
  if (ws_size < 1214464) return;  // signature: absmax 0.3457 -> ws too small

  const int* x     = (const int*)d_in[0];
  const int* tactp = (const int*)d_in[1];
  const int* tstp  = (const int*)d_in[2];
  const int* forcp = (const int*)d_in[3];
  const float* embed = (const float*)d_in[4];
  const float* Wm = (const float*)d_in[5];
  const float* bm = (const float*)d_in[6];
  const float* Wb = (const float*)d_in[7];
  const float* bb = (const float*)d_in[8];
  const float* Ws = (const float*)d_in[9];
  const float* bs = (const float*)d_in[10];

  char* wsp = (char*)d_ws;
  float* Mm32 = (float*)(wsp);             //   17408 B
  float* Ms32 = (float*)(wsp + 17408);     //   32768 B
  float* Mb32 = (float*)(wsp + 50176);     //   65536 B
  float* MmT  = (float*)(wsp + 115712);    //   17408 B
  float* MsT  = (float*)(wsp + 133120);    //   32768 B
  unsigned* lut = (unsigned*)(wsp + 165888);  // 1048576 B -> total 1214464 B

  precompute_M<<<128, 256, 0, stream>>>(embed, Wm, bm, Wb, bb, Ws, bs,
                                        Mm32, Ms32, Mb32, MmT, MsT);
  build_lut<<<2048, 128, 0, stream>>>(Wm, Ws, MmT, MsT, lut);
  sm_fused<<<512, 512, 0, stream>>>(x, tactp, tstp, forcp, lut,
                                    Wm, Wb, Ws, Mm32, Ms32, Mb32,
                                    (float*)d_out);
}